// Round 3
// baseline (188.756 us; speedup 1.0000x reference)
//
#include <hip/hip_runtime.h>

#define BB 16
#define CC 512
#define NN 2048
#define MAXH 70
#define MAXW 40
#define NPIX (MAXH * MAXW)   // 2800
#define BIGC 1000000

// One block per (b, c) plane. Each block redundantly computes the per-sample
// bbox/transpose/shift (ys/xs are tiny and L2-resident), builds the inverse
// map pixel->point in LDS, then fills its output plane by gather.
//
// Semantics notes (matched to JAX/NumPy fancy-index scatter):
//  - negative indices in [-size, 0) WRAP (idx += size) before mode='drop';
//    invalid points use -BIG which stays OOB after wrap -> dropped.
//  - collisions (wrapped vs direct pixels) resolve last-write-wins in n
//    order == largest n wins -> atomicMax on the LDS map.
__global__ __launch_bounds__(256) void fused_map_kernel(
    const float* __restrict__ feat, const float* __restrict__ backend,
    const int* __restrict__ ys, const int* __restrict__ xs,
    float* __restrict__ out)
{
    const int plane = blockIdx.x;          // b*CC + c
    const int b = plane >> 9;              // CC == 512
    const int c = plane & (CC - 1);
    const int tid = threadIdx.x;
    const int* __restrict__ y = ys + b * NN;
    const int* __restrict__ x = xs + b * NN;

    __shared__ int smap[NPIX];             // 11200 B: pixel -> winning point idx (or -1)
    __shared__ int s0[256], s1[256], s2[256], s3[256];

    // init inverse map
    for (int p = tid; p < NPIX; p += 256) smap[p] = -1;

    // bbox reduction over valid points
    int mny = BIGC, mxy = -BIGC, mnx = BIGC, mxx = -BIGC;
    for (int n = tid; n < NN; n += 256) {
        int yy = y[n];
        if (yy > -1) {
            int xx = x[n];
            mny = min(mny, yy); mxy = max(mxy, yy);
            mnx = min(mnx, xx); mxx = max(mxx, xx);
        }
    }
    s0[tid] = mny; s1[tid] = mxy; s2[tid] = mnx; s3[tid] = mxx;
    __syncthreads();
    for (int s = 128; s > 0; s >>= 1) {
        if (tid < s) {
            s0[tid] = min(s0[tid], s0[tid + s]);
            s1[tid] = max(s1[tid], s1[tid + s]);
            s2[tid] = min(s2[tid], s2[tid + s]);
            s3[tid] = max(s3[tid], s3[tid + s]);
        }
        __syncthreads();
    }
    const int min_y = s0[0], max_y = s1[0], min_x = s2[0], max_x = s3[0];
    const int h = max_y - min_y + 1;
    const int w = max_x - min_x + 1;
    const int trans = (w > h) ? 1 : 0;
    const int H2 = trans ? w : h;
    const int W2 = trans ? h : w;
    const int hd = H2 - MAXH;
    const int wd = W2 - MAXW;
    // positive-operand divisions -> C trunc == Python floor
    const int sy = (hd > 0) ? -((hd + 1) / 2) : ((1 - hd) / 2);
    const int sx = (wd > 0) ? -((wd + 1) / 2) : ((1 - wd) / 2);

    // scatter point indices into LDS map with numpy wrap + last-write-wins
    for (int n = tid; n < NN; n += 256) {
        int yy0 = y[n];
        if (yy0 <= -1) continue;           // invalid -> reference used -BIG -> dropped
        int ry = yy0 - min_y;
        int rx = x[n] - min_x;
        int oy = (trans ? rx : ry) + sy;
        int ox = (trans ? ry : rx) + sx;
        if (oy < 0) oy += MAXH;            // numpy negative-index wrap (single)
        if (ox < 0) ox += MAXW;
        if (oy >= 0 && oy < MAXH && ox >= 0 && ox < MAXW)
            atomicMax(&smap[oy * MAXW + ox], n);   // largest n == last write wins
    }
    __syncthreads();

    // fill this plane: gather features via map, backend elsewhere
    const float bv = backend[c];
    const float* __restrict__ frow = feat + (size_t)plane * NN;
    float4* __restrict__ orow4 = (float4*)(out + (size_t)plane * NPIX);

    for (int p4 = tid; p4 < NPIX / 4; p4 += 256) {
        const int base = p4 * 4;
        int a0 = smap[base + 0];
        int a1 = smap[base + 1];
        int a2 = smap[base + 2];
        int a3 = smap[base + 3];
        float4 v;
        v.x = (a0 >= 0) ? frow[a0] : bv;
        v.y = (a1 >= 0) ? frow[a1] : bv;
        v.z = (a2 >= 0) ? frow[a2] : bv;
        v.w = (a3 >= 0) ? frow[a3] : bv;
        orow4[p4] = v;
    }
}

extern "C" void kernel_launch(void* const* d_in, const int* in_sizes, int n_in,
                              void* d_out, int out_size, void* d_ws, size_t ws_size,
                              hipStream_t stream) {
    const float* feat    = (const float*)d_in[0];   // [B, C, N] f32
    const float* backend = (const float*)d_in[1];   // [C, 1, 1] f32
    const int*   ys      = (const int*)d_in[2];     // [B, N] i32
    const int*   xs      = (const int*)d_in[3];     // [B, N] i32
    float* out = (float*)d_out;                     // [B, C, MAXH, MAXW] f32

    fused_map_kernel<<<BB * CC, 256, 0, stream>>>(feat, backend, ys, xs, out);
}

// Round 5
// 185.061 us; speedup vs baseline: 1.0200x; 1.0200x over previous
//
#include <hip/hip_runtime.h>

#define BB 16
#define CC 512
#define NN 2048
#define MAXH 70
#define MAXW 40
#define NPIX (MAXH * MAXW)   // 2800
#define BIGC 1000000

typedef float  f32x4 __attribute__((ext_vector_type(4)));
typedef int    i32x4 __attribute__((ext_vector_type(4)));

// ---------- Kernel 1: per-sample inverse map build (16 blocks) ----------
// srcmap[b, pix] = winning point index n, or -1.
// NumPy fancy-index semantics: negative indices wrap once (+= size) before
// mode='drop'; collisions resolve last-write-wins == largest n (atomicMax).
__global__ __launch_bounds__(256) void build_map_kernel(
    const int* __restrict__ ys, const int* __restrict__ xs,
    int* __restrict__ srcmap)
{
    const int b = blockIdx.x;
    const int tid = threadIdx.x;
    const int* __restrict__ y = ys + b * NN;
    const int* __restrict__ x = xs + b * NN;

    __shared__ int smap[NPIX];
    __shared__ int s0[256], s1[256], s2[256], s3[256];

    for (int p = tid; p < NPIX; p += 256) smap[p] = -1;

    int mny = BIGC, mxy = -BIGC, mnx = BIGC, mxx = -BIGC;
    for (int n = tid; n < NN; n += 256) {
        int yy = y[n];
        if (yy > -1) {
            int xx = x[n];
            mny = min(mny, yy); mxy = max(mxy, yy);
            mnx = min(mnx, xx); mxx = max(mxx, xx);
        }
    }
    s0[tid] = mny; s1[tid] = mxy; s2[tid] = mnx; s3[tid] = mxx;
    __syncthreads();
    for (int s = 128; s > 0; s >>= 1) {
        if (tid < s) {
            s0[tid] = min(s0[tid], s0[tid + s]);
            s1[tid] = max(s1[tid], s1[tid + s]);
            s2[tid] = min(s2[tid], s2[tid + s]);
            s3[tid] = max(s3[tid], s3[tid + s]);
        }
        __syncthreads();
    }
    const int min_y = s0[0], max_y = s1[0], min_x = s2[0], max_x = s3[0];
    const int h = max_y - min_y + 1;
    const int w = max_x - min_x + 1;
    const int trans = (w > h) ? 1 : 0;
    const int H2 = trans ? w : h;
    const int W2 = trans ? h : w;
    const int hd = H2 - MAXH;
    const int wd = W2 - MAXW;
    const int sy = (hd > 0) ? -((hd + 1) / 2) : ((1 - hd) / 2);
    const int sx = (wd > 0) ? -((wd + 1) / 2) : ((1 - wd) / 2);

    for (int n = tid; n < NN; n += 256) {
        int yy0 = y[n];
        if (yy0 <= -1) continue;
        int ry = yy0 - min_y;
        int rx = x[n] - min_x;
        int oy = (trans ? rx : ry) + sy;
        int ox = (trans ? ry : rx) + sx;
        if (oy < 0) oy += MAXH;            // numpy wrap (single; invalid pts excluded above)
        if (ox < 0) ox += MAXW;
        if (oy >= 0 && oy < MAXH && ox >= 0 && ox < MAXW)
            atomicMax(&smap[oy * MAXW + ox], n);
    }
    __syncthreads();

    int* __restrict__ g = srcmap + b * NPIX;
    for (int p = tid; p < NPIX; p += 256) g[p] = smap[p];
}

// ---------- Kernel 2: pure gather fill (no LDS, no syncthreads) ----------
__global__ __launch_bounds__(256) void fill_out_kernel(
    const float* __restrict__ feat, const float* __restrict__ backend,
    const int* __restrict__ srcmap, float* __restrict__ out)
{
    const int plane = blockIdx.x;      // b*CC + c
    const int b = plane >> 9;
    const int c = plane & (CC - 1);
    const float bv = backend[c];
    const float* __restrict__ frow = feat + (size_t)plane * NN;
    const i32x4* __restrict__ smap4 = (const i32x4*)(srcmap + b * NPIX);
    f32x4* __restrict__ orow4 = (f32x4*)(out + (size_t)plane * NPIX);

    for (int p4 = threadIdx.x; p4 < NPIX / 4; p4 += 256) {
        i32x4 s = smap4[p4];
        f32x4 v;
        v.x = (s.x >= 0) ? frow[s.x] : bv;
        v.y = (s.y >= 0) ? frow[s.y] : bv;
        v.z = (s.z >= 0) ? frow[s.z] : bv;
        v.w = (s.w >= 0) ? frow[s.w] : bv;
        __builtin_nontemporal_store(v, &orow4[p4]);
    }
}

// ---------- Fallback: fused single-kernel (passing round-3 version) ----------
__global__ __launch_bounds__(256) void fused_map_kernel(
    const float* __restrict__ feat, const float* __restrict__ backend,
    const int* __restrict__ ys, const int* __restrict__ xs,
    float* __restrict__ out)
{
    const int plane = blockIdx.x;
    const int b = plane >> 9;
    const int c = plane & (CC - 1);
    const int tid = threadIdx.x;
    const int* __restrict__ y = ys + b * NN;
    const int* __restrict__ x = xs + b * NN;

    __shared__ int smap[NPIX];
    __shared__ int s0[256], s1[256], s2[256], s3[256];

    for (int p = tid; p < NPIX; p += 256) smap[p] = -1;

    int mny = BIGC, mxy = -BIGC, mnx = BIGC, mxx = -BIGC;
    for (int n = tid; n < NN; n += 256) {
        int yy = y[n];
        if (yy > -1) {
            int xx = x[n];
            mny = min(mny, yy); mxy = max(mxy, yy);
            mnx = min(mnx, xx); mxx = max(mxx, xx);
        }
    }
    s0[tid] = mny; s1[tid] = mxy; s2[tid] = mnx; s3[tid] = mxx;
    __syncthreads();
    for (int s = 128; s > 0; s >>= 1) {
        if (tid < s) {
            s0[tid] = min(s0[tid], s0[tid + s]);
            s1[tid] = max(s1[tid], s1[tid + s]);
            s2[tid] = min(s2[tid], s2[tid + s]);
            s3[tid] = max(s3[tid], s3[tid + s]);
        }
        __syncthreads();
    }
    const int min_y = s0[0], max_y = s1[0], min_x = s2[0], max_x = s3[0];
    const int h = max_y - min_y + 1;
    const int w = max_x - min_x + 1;
    const int trans = (w > h) ? 1 : 0;
    const int H2 = trans ? w : h;
    const int W2 = trans ? h : w;
    const int hd = H2 - MAXH;
    const int wd = W2 - MAXW;
    const int sy = (hd > 0) ? -((hd + 1) / 2) : ((1 - hd) / 2);
    const int sx = (wd > 0) ? -((wd + 1) / 2) : ((1 - wd) / 2);

    for (int n = tid; n < NN; n += 256) {
        int yy0 = y[n];
        if (yy0 <= -1) continue;
        int ry = yy0 - min_y;
        int rx = x[n] - min_x;
        int oy = (trans ? rx : ry) + sy;
        int ox = (trans ? ry : rx) + sx;
        if (oy < 0) oy += MAXH;
        if (ox < 0) ox += MAXW;
        if (oy >= 0 && oy < MAXH && ox >= 0 && ox < MAXW)
            atomicMax(&smap[oy * MAXW + ox], n);
    }
    __syncthreads();

    const float bv = backend[c];
    const float* __restrict__ frow = feat + (size_t)plane * NN;
    f32x4* __restrict__ orow4 = (f32x4*)(out + (size_t)plane * NPIX);

    for (int p4 = tid; p4 < NPIX / 4; p4 += 256) {
        const int base = p4 * 4;
        int a0 = smap[base + 0];
        int a1 = smap[base + 1];
        int a2 = smap[base + 2];
        int a3 = smap[base + 3];
        f32x4 v;
        v.x = (a0 >= 0) ? frow[a0] : bv;
        v.y = (a1 >= 0) ? frow[a1] : bv;
        v.z = (a2 >= 0) ? frow[a2] : bv;
        v.w = (a3 >= 0) ? frow[a3] : bv;
        orow4[p4] = v;
    }
}

extern "C" void kernel_launch(void* const* d_in, const int* in_sizes, int n_in,
                              void* d_out, int out_size, void* d_ws, size_t ws_size,
                              hipStream_t stream) {
    const float* feat    = (const float*)d_in[0];   // [B, C, N] f32
    const float* backend = (const float*)d_in[1];   // [C, 1, 1] f32
    const int*   ys      = (const int*)d_in[2];     // [B, N] i32
    const int*   xs      = (const int*)d_in[3];     // [B, N] i32
    float* out = (float*)d_out;                     // [B, C, MAXH, MAXW] f32

    const size_t need = (size_t)BB * NPIX * sizeof(int);   // 179,200 B
    if (ws_size >= need) {
        int* srcmap = (int*)d_ws;
        build_map_kernel<<<BB, 256, 0, stream>>>(ys, xs, srcmap);
        fill_out_kernel<<<BB * CC, 256, 0, stream>>>(feat, backend, srcmap, out);
    } else {
        fused_map_kernel<<<BB * CC, 256, 0, stream>>>(feat, backend, ys, xs, out);
    }
}

// Round 6
// 163.671 us; speedup vs baseline: 1.1533x; 1.1307x over previous
//
#include <hip/hip_runtime.h>

#define BB 16
#define CC 512
#define NN 2048
#define MAXH 70
#define MAXW 40
#define NPIX (MAXH * MAXW)   // 2800
#define BIGC 1000000
#define G 4                  // planes per fill block (LDS = G*8KB = 32KB)

typedef float  f32x4 __attribute__((ext_vector_type(4)));
typedef int    i32x4 __attribute__((ext_vector_type(4)));

// ---------- Kernel 1: per-sample inverse map build (16 blocks) ----------
// srcmap[b, pix] = winning point index n, or -1.
// NumPy fancy-index semantics: negative indices wrap once (+= size) before
// mode='drop'; collisions resolve last-write-wins == largest n (atomicMax).
__global__ __launch_bounds__(256) void build_map_kernel(
    const int* __restrict__ ys, const int* __restrict__ xs,
    int* __restrict__ srcmap)
{
    const int b = blockIdx.x;
    const int tid = threadIdx.x;
    const int* __restrict__ y = ys + b * NN;
    const int* __restrict__ x = xs + b * NN;

    __shared__ int smap[NPIX];
    __shared__ int s0[256], s1[256], s2[256], s3[256];

    for (int p = tid; p < NPIX; p += 256) smap[p] = -1;

    int mny = BIGC, mxy = -BIGC, mnx = BIGC, mxx = -BIGC;
    for (int n = tid; n < NN; n += 256) {
        int yy = y[n];
        if (yy > -1) {
            int xx = x[n];
            mny = min(mny, yy); mxy = max(mxy, yy);
            mnx = min(mnx, xx); mxx = max(mxx, xx);
        }
    }
    s0[tid] = mny; s1[tid] = mxy; s2[tid] = mnx; s3[tid] = mxx;
    __syncthreads();
    for (int s = 128; s > 0; s >>= 1) {
        if (tid < s) {
            s0[tid] = min(s0[tid], s0[tid + s]);
            s1[tid] = max(s1[tid], s1[tid + s]);
            s2[tid] = min(s2[tid], s2[tid + s]);
            s3[tid] = max(s3[tid], s3[tid + s]);
        }
        __syncthreads();
    }
    const int min_y = s0[0], max_y = s1[0], min_x = s2[0], max_x = s3[0];
    const int h = max_y - min_y + 1;
    const int w = max_x - min_x + 1;
    const int trans = (w > h) ? 1 : 0;
    const int H2 = trans ? w : h;
    const int W2 = trans ? h : w;
    const int hd = H2 - MAXH;
    const int wd = W2 - MAXW;
    const int sy = (hd > 0) ? -((hd + 1) / 2) : ((1 - hd) / 2);
    const int sx = (wd > 0) ? -((wd + 1) / 2) : ((1 - wd) / 2);

    for (int n = tid; n < NN; n += 256) {
        int yy0 = y[n];
        if (yy0 <= -1) continue;
        int ry = yy0 - min_y;
        int rx = x[n] - min_x;
        int oy = (trans ? rx : ry) + sy;
        int ox = (trans ? ry : rx) + sx;
        if (oy < 0) oy += MAXH;            // numpy wrap (single; invalid pts excluded above)
        if (ox < 0) ox += MAXW;
        if (oy >= 0 && oy < MAXH && ox >= 0 && ox < MAXW)
            atomicMax(&smap[oy * MAXW + ox], n);
    }
    __syncthreads();

    int* __restrict__ g = srcmap + b * NPIX;
    for (int p = tid; p < NPIX; p += 256) g[p] = smap[p];
}

// ---------- Kernel 2: LDS-staged gather fill ----------
// Block = (b, group of G contiguous channels). Stage G planes into LDS with
// coalesced loads; gather from LDS (cheap even when divergent); reuse each
// map int4 across all G planes.
__global__ __launch_bounds__(256) void fill_out_lds_kernel(
    const float* __restrict__ feat, const float* __restrict__ backend,
    const int* __restrict__ srcmap, float* __restrict__ out)
{
    const int grp = blockIdx.x;             // 0 .. BB*CC/G - 1
    const int gpb = CC / G;                 // groups per sample
    const int b  = grp / gpb;
    const int c0 = (grp - b * gpb) * G;
    const int tid = threadIdx.x;

    __shared__ float sfeat[G * NN];         // 32 KB

    // stage G contiguous planes: feat[b, c0 .. c0+G-1, :]
    const f32x4* __restrict__ fsrc = (const f32x4*)(feat + ((size_t)b * CC + c0) * NN);
    f32x4* __restrict__ sdst = (f32x4*)sfeat;
    #pragma unroll
    for (int i = 0; i < G * NN / 4 / 256; ++i)
        sdst[tid + i * 256] = fsrc[tid + i * 256];
    __syncthreads();

    float bv[G];
    #pragma unroll
    for (int g = 0; g < G; ++g) bv[g] = backend[c0 + g];

    const i32x4* __restrict__ smap4 = (const i32x4*)(srcmap + b * NPIX);
    f32x4* __restrict__ obase = (f32x4*)(out + ((size_t)b * CC + c0) * NPIX);

    for (int p4 = tid; p4 < NPIX / 4; p4 += 256) {
        i32x4 s = smap4[p4];
        #pragma unroll
        for (int g = 0; g < G; ++g) {
            const float* sf = sfeat + g * NN;
            f32x4 v;
            v.x = (s.x >= 0) ? sf[s.x] : bv[g];
            v.y = (s.y >= 0) ? sf[s.y] : bv[g];
            v.z = (s.z >= 0) ? sf[s.z] : bv[g];
            v.w = (s.w >= 0) ? sf[s.w] : bv[g];
            __builtin_nontemporal_store(v, obase + (size_t)g * (NPIX / 4) + p4);
        }
    }
}

// ---------- Fallback: fused single-kernel (passing round-3 version) ----------
__global__ __launch_bounds__(256) void fused_map_kernel(
    const float* __restrict__ feat, const float* __restrict__ backend,
    const int* __restrict__ ys, const int* __restrict__ xs,
    float* __restrict__ out)
{
    const int plane = blockIdx.x;
    const int b = plane >> 9;
    const int c = plane & (CC - 1);
    const int tid = threadIdx.x;
    const int* __restrict__ y = ys + b * NN;
    const int* __restrict__ x = xs + b * NN;

    __shared__ int smap[NPIX];
    __shared__ int s0[256], s1[256], s2[256], s3[256];

    for (int p = tid; p < NPIX; p += 256) smap[p] = -1;

    int mny = BIGC, mxy = -BIGC, mnx = BIGC, mxx = -BIGC;
    for (int n = tid; n < NN; n += 256) {
        int yy = y[n];
        if (yy > -1) {
            int xx = x[n];
            mny = min(mny, yy); mxy = max(mxy, yy);
            mnx = min(mnx, xx); mxx = max(mxx, xx);
        }
    }
    s0[tid] = mny; s1[tid] = mxy; s2[tid] = mnx; s3[tid] = mxx;
    __syncthreads();
    for (int s = 128; s > 0; s >>= 1) {
        if (tid < s) {
            s0[tid] = min(s0[tid], s0[tid + s]);
            s1[tid] = max(s1[tid], s1[tid + s]);
            s2[tid] = min(s2[tid], s2[tid + s]);
            s3[tid] = max(s3[tid], s3[tid + s]);
        }
        __syncthreads();
    }
    const int min_y = s0[0], max_y = s1[0], min_x = s2[0], max_x = s3[0];
    const int h = max_y - min_y + 1;
    const int w = max_x - min_x + 1;
    const int trans = (w > h) ? 1 : 0;
    const int H2 = trans ? w : h;
    const int W2 = trans ? h : w;
    const int hd = H2 - MAXH;
    const int wd = W2 - MAXW;
    const int sy = (hd > 0) ? -((hd + 1) / 2) : ((1 - hd) / 2);
    const int sx = (wd > 0) ? -((wd + 1) / 2) : ((1 - wd) / 2);

    for (int n = tid; n < NN; n += 256) {
        int yy0 = y[n];
        if (yy0 <= -1) continue;
        int ry = yy0 - min_y;
        int rx = x[n] - min_x;
        int oy = (trans ? rx : ry) + sy;
        int ox = (trans ? ry : rx) + sx;
        if (oy < 0) oy += MAXH;
        if (ox < 0) ox += MAXW;
        if (oy >= 0 && oy < MAXH && ox >= 0 && ox < MAXW)
            atomicMax(&smap[oy * MAXW + ox], n);
    }
    __syncthreads();

    const float bv = backend[c];
    const float* __restrict__ frow = feat + (size_t)plane * NN;
    f32x4* __restrict__ orow4 = (f32x4*)(out + (size_t)plane * NPIX);

    for (int p4 = tid; p4 < NPIX / 4; p4 += 256) {
        const int base = p4 * 4;
        int a0 = smap[base + 0];
        int a1 = smap[base + 1];
        int a2 = smap[base + 2];
        int a3 = smap[base + 3];
        f32x4 v;
        v.x = (a0 >= 0) ? frow[a0] : bv;
        v.y = (a1 >= 0) ? frow[a1] : bv;
        v.z = (a2 >= 0) ? frow[a2] : bv;
        v.w = (a3 >= 0) ? frow[a3] : bv;
        orow4[p4] = v;
    }
}

extern "C" void kernel_launch(void* const* d_in, const int* in_sizes, int n_in,
                              void* d_out, int out_size, void* d_ws, size_t ws_size,
                              hipStream_t stream) {
    const float* feat    = (const float*)d_in[0];   // [B, C, N] f32
    const float* backend = (const float*)d_in[1];   // [C, 1, 1] f32
    const int*   ys      = (const int*)d_in[2];     // [B, N] i32
    const int*   xs      = (const int*)d_in[3];     // [B, N] i32
    float* out = (float*)d_out;                     // [B, C, MAXH, MAXW] f32

    const size_t need = (size_t)BB * NPIX * sizeof(int);   // 179,200 B
    if (ws_size >= need) {
        int* srcmap = (int*)d_ws;
        build_map_kernel<<<BB, 256, 0, stream>>>(ys, xs, srcmap);
        fill_out_lds_kernel<<<BB * CC / G, 256, 0, stream>>>(feat, backend, srcmap, out);
    } else {
        fused_map_kernel<<<BB * CC, 256, 0, stream>>>(feat, backend, ys, xs, out);
    }
}

// Round 7
// 155.939 us; speedup vs baseline: 1.2104x; 1.0496x over previous
//
#include <hip/hip_runtime.h>

#define BB 16
#define CC 512
#define NN 2048
#define MAXH 70
#define MAXW 40
#define NPIX (MAXH * MAXW)   // 2800
#define BIGC 1000000
#define G 4                  // planes per fill block (LDS = G*8KB = 32KB)

typedef float  f32x4 __attribute__((ext_vector_type(4)));
typedef int    i32x4 __attribute__((ext_vector_type(4)));

// ---------- Kernel 1: per-sample inverse map build (16 blocks) ----------
// srcmap[b, pix] = winning point index n, or -1.
// NumPy fancy-index semantics: negative indices wrap once (+= size) before
// mode='drop'; collisions resolve last-write-wins == largest n (atomicMax).
__global__ __launch_bounds__(256) void build_map_kernel(
    const int* __restrict__ ys, const int* __restrict__ xs,
    int* __restrict__ srcmap)
{
    const int b = blockIdx.x;
    const int tid = threadIdx.x;
    const int* __restrict__ y = ys + b * NN;
    const int* __restrict__ x = xs + b * NN;

    __shared__ int smap[NPIX];
    __shared__ int s0[256], s1[256], s2[256], s3[256];

    for (int p = tid; p < NPIX; p += 256) smap[p] = -1;

    int mny = BIGC, mxy = -BIGC, mnx = BIGC, mxx = -BIGC;
    for (int n = tid; n < NN; n += 256) {
        int yy = y[n];
        if (yy > -1) {
            int xx = x[n];
            mny = min(mny, yy); mxy = max(mxy, yy);
            mnx = min(mnx, xx); mxx = max(mxx, xx);
        }
    }
    s0[tid] = mny; s1[tid] = mxy; s2[tid] = mnx; s3[tid] = mxx;
    __syncthreads();
    for (int s = 128; s > 0; s >>= 1) {
        if (tid < s) {
            s0[tid] = min(s0[tid], s0[tid + s]);
            s1[tid] = max(s1[tid], s1[tid + s]);
            s2[tid] = min(s2[tid], s2[tid + s]);
            s3[tid] = max(s3[tid], s3[tid + s]);
        }
        __syncthreads();
    }
    const int min_y = s0[0], max_y = s1[0], min_x = s2[0], max_x = s3[0];
    const int h = max_y - min_y + 1;
    const int w = max_x - min_x + 1;
    const int trans = (w > h) ? 1 : 0;
    const int H2 = trans ? w : h;
    const int W2 = trans ? h : w;
    const int hd = H2 - MAXH;
    const int wd = W2 - MAXW;
    const int sy = (hd > 0) ? -((hd + 1) / 2) : ((1 - hd) / 2);
    const int sx = (wd > 0) ? -((wd + 1) / 2) : ((1 - wd) / 2);

    for (int n = tid; n < NN; n += 256) {
        int yy0 = y[n];
        if (yy0 <= -1) continue;
        int ry = yy0 - min_y;
        int rx = x[n] - min_x;
        int oy = (trans ? rx : ry) + sy;
        int ox = (trans ? ry : rx) + sx;
        if (oy < 0) oy += MAXH;            // numpy wrap (single; invalid pts excluded above)
        if (ox < 0) ox += MAXW;
        if (oy >= 0 && oy < MAXH && ox >= 0 && ox < MAXW)
            atomicMax(&smap[oy * MAXW + ox], n);
    }
    __syncthreads();

    int* __restrict__ g = srcmap + b * NPIX;
    for (int p = tid; p < NPIX; p += 256) g[p] = smap[p];
}

// ---------- Kernel 2: LDS-staged gather fill (512 thr, 32KB LDS) ----------
// 4 blocks/CU = 32 waves/CU (max). Map int4 loads hoisted BEFORE the stage
// so their L2 latency hides under the staging burst. Feat staging loads are
// nontemporal (single-use — keep L2 for map + write combining).
__global__ __launch_bounds__(512) void fill_out_lds_kernel(
    const float* __restrict__ feat, const float* __restrict__ backend,
    const int* __restrict__ srcmap, float* __restrict__ out)
{
    const int grp = blockIdx.x;             // 0 .. BB*CC/G - 1
    const int gpb = CC / G;                 // groups per sample
    const int b  = grp / gpb;
    const int c0 = (grp - b * gpb) * G;
    const int tid = threadIdx.x;

    __shared__ float sfeat[G * NN];         // 32 KB

    // early map loads: p4a always valid (tid < 512 <= 700), p4b tail-guarded
    const i32x4* __restrict__ smap4 = (const i32x4*)(srcmap + b * NPIX);
    const int p4a = tid;
    const int p4b = tid + 512;
    const bool hasB = (p4b < NPIX / 4);
    i32x4 sA = smap4[p4a];
    i32x4 sB = smap4[hasB ? p4b : 0];

    // stage G contiguous planes: feat[b, c0 .. c0+G-1, :]
    const f32x4* __restrict__ fsrc = (const f32x4*)(feat + ((size_t)b * CC + c0) * NN);
    f32x4* __restrict__ sdst = (f32x4*)sfeat;
    #pragma unroll
    for (int i = 0; i < G * NN / 4 / 512; ++i) {   // 4 iters
        f32x4 t = __builtin_nontemporal_load(&fsrc[tid + i * 512]);
        sdst[tid + i * 512] = t;
    }

    float bv[G];
    #pragma unroll
    for (int g = 0; g < G; ++g) bv[g] = backend[c0 + g];

    __syncthreads();

    f32x4* __restrict__ obase = (f32x4*)(out + ((size_t)b * CC + c0) * NPIX);

    #pragma unroll
    for (int g = 0; g < G; ++g) {
        const float* sf = sfeat + g * NN;
        f32x4 v;
        v.x = (sA.x >= 0) ? sf[sA.x] : bv[g];
        v.y = (sA.y >= 0) ? sf[sA.y] : bv[g];
        v.z = (sA.z >= 0) ? sf[sA.z] : bv[g];
        v.w = (sA.w >= 0) ? sf[sA.w] : bv[g];
        __builtin_nontemporal_store(v, obase + (size_t)g * (NPIX / 4) + p4a);
    }
    if (hasB) {
        #pragma unroll
        for (int g = 0; g < G; ++g) {
            const float* sf = sfeat + g * NN;
            f32x4 v;
            v.x = (sB.x >= 0) ? sf[sB.x] : bv[g];
            v.y = (sB.y >= 0) ? sf[sB.y] : bv[g];
            v.z = (sB.z >= 0) ? sf[sB.z] : bv[g];
            v.w = (sB.w >= 0) ? sf[sB.w] : bv[g];
            __builtin_nontemporal_store(v, obase + (size_t)g * (NPIX / 4) + p4b);
        }
    }
}

// ---------- Fallback: fused single-kernel (passing round-3 version) ----------
__global__ __launch_bounds__(256) void fused_map_kernel(
    const float* __restrict__ feat, const float* __restrict__ backend,
    const int* __restrict__ ys, const int* __restrict__ xs,
    float* __restrict__ out)
{
    const int plane = blockIdx.x;
    const int b = plane >> 9;
    const int c = plane & (CC - 1);
    const int tid = threadIdx.x;
    const int* __restrict__ y = ys + b * NN;
    const int* __restrict__ x = xs + b * NN;

    __shared__ int smap[NPIX];
    __shared__ int s0[256], s1[256], s2[256], s3[256];

    for (int p = tid; p < NPIX; p += 256) smap[p] = -1;

    int mny = BIGC, mxy = -BIGC, mnx = BIGC, mxx = -BIGC;
    for (int n = tid; n < NN; n += 256) {
        int yy = y[n];
        if (yy > -1) {
            int xx = x[n];
            mny = min(mny, yy); mxy = max(mxy, yy);
            mnx = min(mnx, xx); mxx = max(mxx, xx);
        }
    }
    s0[tid] = mny; s1[tid] = mxy; s2[tid] = mnx; s3[tid] = mxx;
    __syncthreads();
    for (int s = 128; s > 0; s >>= 1) {
        if (tid < s) {
            s0[tid] = min(s0[tid], s0[tid + s]);
            s1[tid] = max(s1[tid], s1[tid + s]);
            s2[tid] = min(s2[tid], s2[tid + s]);
            s3[tid] = max(s3[tid], s3[tid + s]);
        }
        __syncthreads();
    }
    const int min_y = s0[0], max_y = s1[0], min_x = s2[0], max_x = s3[0];
    const int h = max_y - min_y + 1;
    const int w = max_x - min_x + 1;
    const int trans = (w > h) ? 1 : 0;
    const int H2 = trans ? w : h;
    const int W2 = trans ? h : w;
    const int hd = H2 - MAXH;
    const int wd = W2 - MAXW;
    const int sy = (hd > 0) ? -((hd + 1) / 2) : ((1 - hd) / 2);
    const int sx = (wd > 0) ? -((wd + 1) / 2) : ((1 - wd) / 2);

    for (int n = tid; n < NN; n += 256) {
        int yy0 = y[n];
        if (yy0 <= -1) continue;
        int ry = yy0 - min_y;
        int rx = x[n] - min_x;
        int oy = (trans ? rx : ry) + sy;
        int ox = (trans ? ry : rx) + sx;
        if (oy < 0) oy += MAXH;
        if (ox < 0) ox += MAXW;
        if (oy >= 0 && oy < MAXH && ox >= 0 && ox < MAXW)
            atomicMax(&smap[oy * MAXW + ox], n);
    }
    __syncthreads();

    const float bv = backend[c];
    const float* __restrict__ frow = feat + (size_t)plane * NN;
    f32x4* __restrict__ orow4 = (f32x4*)(out + (size_t)plane * NPIX);

    for (int p4 = tid; p4 < NPIX / 4; p4 += 256) {
        const int base = p4 * 4;
        int a0 = smap[base + 0];
        int a1 = smap[base + 1];
        int a2 = smap[base + 2];
        int a3 = smap[base + 3];
        f32x4 v;
        v.x = (a0 >= 0) ? frow[a0] : bv;
        v.y = (a1 >= 0) ? frow[a1] : bv;
        v.z = (a2 >= 0) ? frow[a2] : bv;
        v.w = (a3 >= 0) ? frow[a3] : bv;
        orow4[p4] = v;
    }
}

extern "C" void kernel_launch(void* const* d_in, const int* in_sizes, int n_in,
                              void* d_out, int out_size, void* d_ws, size_t ws_size,
                              hipStream_t stream) {
    const float* feat    = (const float*)d_in[0];   // [B, C, N] f32
    const float* backend = (const float*)d_in[1];   // [C, 1, 1] f32
    const int*   ys      = (const int*)d_in[2];     // [B, N] i32
    const int*   xs      = (const int*)d_in[3];     // [B, N] i32
    float* out = (float*)d_out;                     // [B, C, MAXH, MAXW] f32

    const size_t need = (size_t)BB * NPIX * sizeof(int);   // 179,200 B
    if (ws_size >= need) {
        int* srcmap = (int*)d_ws;
        build_map_kernel<<<BB, 256, 0, stream>>>(ys, xs, srcmap);
        fill_out_lds_kernel<<<BB * CC / G, 512, 0, stream>>>(feat, backend, srcmap, out);
    } else {
        fused_map_kernel<<<BB * CC, 256, 0, stream>>>(feat, backend, ys, xs, out);
    }
}